// Round 3
// baseline (74.403 us; speedup 1.0000x reference)
//
#include <hip/hip_runtime.h>

#ifndef __has_builtin
#define __has_builtin(x) 0
#endif

__device__ __forceinline__ float fexp2(float x) {
#if __has_builtin(__builtin_amdgcn_exp2f)
    return __builtin_amdgcn_exp2f(x);
#else
    return exp2f(x);
#endif
}
__device__ __forceinline__ float frcp(float x) {
#if __has_builtin(__builtin_amdgcn_rcpf)
    return __builtin_amdgcn_rcpf(x);
#else
    return 1.0f / x;
#endif
}

constexpr int TT = 32;   // directions T
constexpr int SS = 32;   // steps S
constexpr int BB = 64;   // graphs B
constexpr int NB = 64;   // partition blocks for edge sort
constexpr int CPB_N = 8;   // chunks per graph, node part
constexpr int CPB_E = 16;  // chunks per graph, edge part
constexpr float SL2E = 50.0f * 1.44269504088896340736f;

// ---- fused prep: node heights nh[N][32] + graph bounds + edge histogram ----
__global__ __launch_bounds__(256) void prep_k(
    const float* __restrict__ x, const float* __restrict__ v,
    const int* __restrict__ batch, const int* __restrict__ src,
    int N, int E, int nhB,
    float* __restrict__ nh, int* __restrict__ starts, int* __restrict__ hist)
{
    if ((int)blockIdx.x < nhB) {
        const int n = blockIdx.x * 256 + threadIdx.x;
        if (n >= N) return;
        const float a0 = x[3 * n], a1 = x[3 * n + 1], a2 = x[3 * n + 2];
        float4 o[8];
#pragma unroll
        for (int t = 0; t < TT; ++t)
            ((float*)o)[t] = fmaf(a0, v[t], fmaf(a1, v[TT + t], a2 * v[2 * TT + t]));
        float4* d4 = (float4*)(nh + (size_t)n * TT);
#pragma unroll
        for (int q = 0; q < 8; ++q) d4[q] = o[q];
        // graph boundary detection (batch is sorted)
        const int g = batch[n];
        const int gp = (n == 0) ? -1 : batch[n - 1];
        for (int g2 = gp + 1; g2 <= g; ++g2) starts[g2] = n;
        if (n == N - 1)
            for (int g2 = g + 1; g2 <= BB; ++g2) starts[g2] = N;
    } else {
        const int b = blockIdx.x - nhB;
        __shared__ int h[BB];
        if (threadIdx.x < BB) h[threadIdx.x] = 0;
        __syncthreads();
        const int per = (E + NB - 1) / NB;
        const int lo = b * per, hi = min(E, lo + per);
        for (int e = lo + threadIdx.x; e < hi; e += 256)
            atomicAdd(&h[batch[src[e]]], 1);
        __syncthreads();
        if (threadIdx.x < BB) hist[b * BB + threadIdx.x] = h[threadIdx.x];
    }
}

// ---- scan hist[b][g] -> base[b][g] (graph offsets folded) + offs[0..BB] ----
__global__ void scan_k(const int* __restrict__ hist,
                       int* __restrict__ base, int* __restrict__ offs) {
    __shared__ int sbase[NB][BB + 1];
    __shared__ int tot[BB];
    const int g = threadIdx.x;   // 64 threads
    int acc = 0;
    for (int b = 0; b < NB; ++b) { sbase[b][g] = acc; acc += hist[b * BB + g]; }
    tot[g] = acc;
    __syncthreads();
    if (g == 0) {
        int run = 0;
        for (int i = 0; i < BB; ++i) { offs[i] = run; run += tot[i]; tot[i] = offs[i]; }
        offs[BB] = run;
    }
    __syncthreads();
    const int o = tot[g];
    for (int b = 0; b < NB; ++b) base[b * BB + g] = sbase[b][g] + o;
}

// ---- scatter edge endpoints grouped by graph (LDS cursors, no global atomics) ----
__global__ __launch_bounds__(256) void scatter_k(
    const int* __restrict__ src, const int* __restrict__ dst,
    const int* __restrict__ batch, int E, const int* __restrict__ base,
    int* __restrict__ ssrc, int* __restrict__ sdst)
{
    __shared__ int lcur[BB];
    if (threadIdx.x < BB) lcur[threadIdx.x] = base[blockIdx.x * BB + threadIdx.x];
    __syncthreads();
    const int per = (E + NB - 1) / NB;
    const int lo = blockIdx.x * per, hi = min(E, lo + per);
    for (int e = lo + threadIdx.x; e < hi; e += 256) {
        const int s = src[e], d = dst[e];
        const int pos = atomicAdd(&lcur[batch[s]], 1);
        ssrc[pos] = s;
        sdst[pos] = d;
    }
}

// ---- fused ECT pass: node blocks then edge blocks; no LDS, no barriers ----
// Thread owns (t = tid&31, 4 consecutive s = 4*(tid>>5)+k).
// sigmoid(50(lin-h)) = 1/(1+exp2(m-ck)); u_k chained off u_0 by constant factors.
__global__ __launch_bounds__(256) void ect_k(
    const float* __restrict__ nh, const float* __restrict__ lin,
    const int* __restrict__ ssrc, const int* __restrict__ sdst,
    const int* __restrict__ starts, const int* __restrict__ offs,
    float* __restrict__ out)
{
    const bool edge = blockIdx.x >= BB * CPB_N;
    const int bid = edge ? blockIdx.x - BB * CPB_N : blockIdx.x;
    const int CPB = edge ? CPB_E : CPB_N;
    const int g = bid / CPB;
    const int c = bid % CPB;
    const int* bnds = edge ? offs : starts;
    const int s0 = bnds[g], s1 = bnds[g + 1];
    const int chunk = (s1 - s0 + CPB - 1) / CPB;
    const int lo = s0 + c * chunk;
    const int hi = min(s1, lo + chunk);

    const int t = threadIdx.x & 31;
    const int r = threadIdx.x >> 5;          // s-group 0..7, s = 4r+k
    const float l0 = lin[4 * r];
    const float ck0 = SL2E * l0;
    const float ch1 = fexp2(SL2E * (l0 - lin[4 * r + 1]));
    const float ch2 = fexp2(SL2E * (l0 - lin[4 * r + 2]));
    const float ch3 = fexp2(SL2E * (l0 - lin[4 * r + 3]));

    float acc0 = 0.f, acc1 = 0.f, acc2 = 0.f, acc3 = 0.f;

    if (!edge) {
#pragma unroll 4
        for (int e = lo; e < hi; ++e) {
            const float h = nh[(size_t)e * TT + t];
            const float u0 = fexp2(fmaf(h, SL2E, -ck0));
            acc0 += frcp(1.0f + u0);
            acc1 += frcp(fmaf(u0, ch1, 1.0f));
            acc2 += frcp(fmaf(u0, ch2, 1.0f));
            acc3 += frcp(fmaf(u0, ch3, 1.0f));
        }
    } else {
#pragma unroll 4
        for (int e = lo; e < hi; ++e) {
            const int sn = ssrc[e], dn = sdst[e];   // wave-uniform -> scalar loads
            const float h = fmaxf(nh[(size_t)sn * TT + t], nh[(size_t)dn * TT + t]);
            const float u0 = fexp2(fmaf(h, SL2E, -ck0));
            acc0 += frcp(1.0f + u0);
            acc1 += frcp(fmaf(u0, ch1, 1.0f));
            acc2 += frcp(fmaf(u0, ch2, 1.0f));
            acc3 += frcp(fmaf(u0, ch3, 1.0f));
        }
    }

    const float sign = edge ? -1.0f : 1.0f;
    float* o = out + ((size_t)g * SS + 4 * r) * TT + t;
    atomicAdd(o,          sign * acc0);
    atomicAdd(o + TT,     sign * acc1);
    atomicAdd(o + 2 * TT, sign * acc2);
    atomicAdd(o + 3 * TT, sign * acc3);
}

extern "C" void kernel_launch(void* const* d_in, const int* in_sizes, int n_in,
                              void* d_out, int out_size, void* d_ws, size_t ws_size,
                              hipStream_t stream) {
    const float* x   = (const float*)d_in[0];
    const float* v   = (const float*)d_in[1];
    const float* lin = (const float*)d_in[2];
    const int* edge_index = (const int*)d_in[3];
    const int* batch = (const int*)d_in[4];

    const int N = in_sizes[0] / 3;
    const int E = in_sizes[3] / 2;
    const int* src = edge_index;       // edge_index[0][:]
    const int* dst = edge_index + E;   // edge_index[1][:]
    float* out = (float*)d_out;

    char* ws = (char*)d_ws;
    int* starts = (int*)ws;                       // 65 ints
    int* offs   = (int*)(ws + 512);               // 65 ints
    int* hist   = (int*)(ws + 1024);              // NB*BB
    int* base   = (int*)(ws + 1024 + NB * BB * 4);// NB*BB
    int* ssrc   = (int*)(ws + 65536);             // E
    int* sdst   = ssrc + E;                       // E
    float* nh   = (float*)(ws + 65536 + 2 * ((size_t)E * 4 + 255) / 256 * 256); // N*32 f32

    hipMemsetAsync(out, 0, (size_t)out_size * sizeof(float), stream);

    const int nhB = (N + 255) / 256;
    prep_k<<<nhB + NB, 256, 0, stream>>>(x, v, batch, src, N, E, nhB, nh, starts, hist);
    scan_k<<<1, BB, 0, stream>>>(hist, base, offs);
    scatter_k<<<NB, 256, 0, stream>>>(src, dst, batch, E, base, ssrc, sdst);
    ect_k<<<BB * (CPB_N + CPB_E), 256, 0, stream>>>(nh, lin, ssrc, sdst, starts, offs, out);
}